// Round 6
// baseline (409.528 us; speedup 1.0000x reference)
//
#include <hip/hip_runtime.h>

typedef short short8 __attribute__((ext_vector_type(8)));
typedef float f32x4 __attribute__((ext_vector_type(4)));
typedef unsigned short ushort4v __attribute__((ext_vector_type(4)));

__device__ __forceinline__ unsigned short f2bf(float f) {
  unsigned int u = __builtin_bit_cast(unsigned int, f);
  u += 0x7fffu + ((u >> 16) & 1u);   // round-to-nearest-even
  return (unsigned short)(u >> 16);
}

// DPP row_shr add: v += lane(i-N) within the 16-lane row (zero-fill OOB).
// After 0x114,0x112,0x111 lane 7 (resp. 15) holds the sum of lanes 0-7
// (resp. 8-15): expanding the shifts, lane 15 = a[8..15], lane 7 = a[0..7].
template <int CTRL>
__device__ __forceinline__ float dpp_add(float v) {
  int t = __builtin_amdgcn_update_dpp(0, __builtin_bit_cast(int, v), CTRL, 0xf, 0xf, true);
  return v + __builtin_bit_cast(float, t);
}

// ---- prep: transpose w_off [pos][c][18] -> wT [pos][18][c], convert w_out
// [576][128] fp32 -> wbt [128][576] bf16 (B^T for the GEMM).
__global__ __launch_bounds__(256) void prep(const float* __restrict__ w_off,
                                            const float* __restrict__ w_out,
                                            float* __restrict__ wT,
                                            unsigned short* __restrict__ wbt) {
  int i = blockIdx.x * 256 + threadIdx.x;
  if (i < 73728) {  // 576*128
    int k = i >> 7, n = i & 127;
    wbt[n * 576 + k] = f2bf(w_out[i]);
  }
  int t = i - 73728;
  if (t >= 0 && t < 10368) {  // 9*64*18
    int pos = t / 1152, r = t - pos * 1152;
    int c = r / 18, j = r - c * 18;
    wT[(pos * 18 + j) * 64 + c] = w_off[t];
  }
}

// ---- offset conv v6: v4 dataflow (pair/thread, acc[18][2], proven 56 VGPR
// no-spill) + wT staged in LDS + 1024-thread blocks.
// History: v2 full unroll -> load-batch spills. v3 partial unroll -> runtime
// acc index -> scratch. v4 (107us): clean, but 36/40 VMEM per tap were wT
// re-reads thrashing L1 at 13 waves/CU (VALUBusy 34%). v5 quad/thread ->
// acc[18][4]=72 > 64-VGPR target -> spilled again (WRITE 41MB), regressed.
// v6: w loads -> LDS (wave-uniform broadcast, conflict-free); 1024-thread
// blocks amortize the 41.5KB stage and give 2 blocks/CU = 32 waves at
// VGPR<=64. VALU-bound target ~19us + overhead.
__global__ __launch_bounds__(1024, 8) void offconv6(const float* __restrict__ x,
                                                    const float* __restrict__ wT,
                                                    const float* __restrict__ b_off,
                                                    float* __restrict__ offs) {
  __shared__ float lw[10368];  // [tap][18][64] = 41,472 B
  const int tid = threadIdx.x;
#pragma unroll 1
  for (int i = tid; i < 2592; i += 1024)
    *(float4*)&lw[i * 4] = *(const float4*)&wT[i * 4];
  __syncthreads();

  const int img = blockIdx.x & 7;        // image -> XCD chunk
  const int blk = blockIdx.x >> 3;       // 0..63 within image (2 rows each)
  const int pairLocal = tid >> 3;        // 0..127
  const int c8 = tid & 7;                // channel group
  const int p = img * 16384 + blk * 256 + pairLocal * 2;
  const int hw = p & 16383, h = hw >> 7, w0 = hw & 127;

  float acc[18][2];
#pragma unroll
  for (int j = 0; j < 18; ++j) {
    float bj = b_off[j];
    acc[j][0] = bj;
    acc[j][1] = bj;
  }

  const float* xim = x + (size_t)img * (128 * 128 * 64);
  const int ca = c8 * 4;  // this lane's channels: ca..ca+3, ca+32..ca+35

#pragma unroll 1
  for (int kh = 0; kh < 3; ++kh) {
    const int hh = h + kh - 1;
    const bool rok = (hh >= 0) && (hh <= 127);
    const int hc = hh < 0 ? 0 : (hh > 127 ? 127 : hh);
#pragma unroll 1
    for (int kw = 0; kw < 3; ++kw) {
      const int ww0 = w0 + kw - 1;  // in [-1,127] (w0 even <= 126)
      const int ww1 = ww0 + 1;      // in [0,128]
      const bool ok0 = rok && (ww0 >= 0);
      const bool ok1 = rok && (ww1 <= 127);
      const int wc0 = ww0 < 0 ? 0 : ww0;
      const int wc1 = ww1 > 127 ? 127 : ww1;
      const float* x0 = xim + (size_t)(hc * 128 + wc0) * 64 + ca;
      const float* x1 = xim + (size_t)(hc * 128 + wc1) * 64 + ca;
      float4 xa0 = *(const float4*)x0;
      float4 xb0 = *(const float4*)(x0 + 32);
      float4 xa1 = *(const float4*)x1;
      float4 xb1 = *(const float4*)(x1 + 32);
      if (!ok0) { xa0 = make_float4(0.f, 0.f, 0.f, 0.f); xb0 = xa0; }
      if (!ok1) { xa1 = make_float4(0.f, 0.f, 0.f, 0.f); xb1 = xa1; }
      const float* wp = lw + ((kh * 3 + kw) * 18) * 64 + ca;
#pragma unroll
      for (int j = 0; j < 18; ++j) {  // FULL unroll: acc index is static
        float4 wa = *(const float4*)(wp + j * 64);
        float4 wb = *(const float4*)(wp + j * 64 + 32);
        float a0 = acc[j][0], a1 = acc[j][1];
        a0 = fmaf(xa0.x, wa.x, a0);
        a0 = fmaf(xa0.y, wa.y, a0);
        a0 = fmaf(xa0.z, wa.z, a0);
        a0 = fmaf(xa0.w, wa.w, a0);
        a0 = fmaf(xb0.x, wb.x, a0);
        a0 = fmaf(xb0.y, wb.y, a0);
        a0 = fmaf(xb0.z, wb.z, a0);
        a0 = fmaf(xb0.w, wb.w, a0);
        a1 = fmaf(xa1.x, wa.x, a1);
        a1 = fmaf(xa1.y, wa.y, a1);
        a1 = fmaf(xa1.z, wa.z, a1);
        a1 = fmaf(xa1.w, wa.w, a1);
        a1 = fmaf(xb1.x, wb.x, a1);
        a1 = fmaf(xb1.y, wb.y, a1);
        a1 = fmaf(xb1.z, wb.z, a1);
        a1 = fmaf(xb1.w, wb.w, a1);
        acc[j][0] = a0;
        acc[j][1] = a1;
      }
    }
  }

  // reduce channel partials across the 8 c8-lanes; total lands in c8==7.
#pragma unroll
  for (int j = 0; j < 18; ++j) {
#pragma unroll
    for (int q = 0; q < 2; ++q) {
      float v = acc[j][q];
      v = dpp_add<0x114>(v);  // row_shr:4
      v = dpp_add<0x112>(v);  // row_shr:2
      v = dpp_add<0x111>(v);  // row_shr:1
      acc[j][q] = v;
    }
  }
  if (c8 == 7) {
    float* op = offs + (size_t)p * 18;
#pragma unroll
    for (int j = 0; j < 18; ++j) {
      op[j] = acc[j][0];
      op[18 + j] = acc[j][1];
    }
  }
}

// ---- bilinear sampling v2: lane = 4 channels (float4), 16-lane group per
// (pixel, tap), wave covers 4 taps. (R3: v1 was VALU-issue-bound at 86%;
// v2 amortizes per-tap scalar math 4x and cuts VMEM instrs 4x.)
__global__ __launch_bounds__(256) void sample2(const float* __restrict__ x,
                                               const float* __restrict__ offs,
                                               unsigned short* __restrict__ sampled,
                                               int p0) {
  int gid = blockIdx.x * 256 + threadIdx.x;
  int grp = gid & 15;        // channel group: channels grp*4 .. grp*4+3
  int tt = gid >> 4;         // tap-task index (relative)
  int pr = tt / 9;           // pixel relative to p0 (magic-mul div)
  int tap = tt - pr * 9;
  int p = p0 + pr;
  int b = p >> 14, hw = p & 16383, h = hw >> 7, w = hw & 127;
  float2 o = *(const float2*)(offs + (size_t)p * 18 + tap * 2);
  float fx = fminf(fmaxf((float)w + o.x, 0.f), 127.f);
  float fy = fminf(fmaxf((float)h + o.y, 0.f), 127.f);
  float x0 = floorf(fx), y0 = floorf(fy);
  float x1 = fminf(x0 + 1.f, 127.f), y1 = fminf(y0 + 1.f, 127.f);
  float wx1 = x1 - fx, wx0 = fx - x0;
  float wy1 = y1 - fy, wy0 = fy - y0;
  float wa = wx1 * wy1, wb = wx1 * wy0, wc = wx0 * wy1, wd = wx0 * wy0;
  int ix0 = (int)x0, ix1 = (int)x1, iy0 = (int)y0, iy1 = (int)y1;
  const float* xb = x + (size_t)b * (128 * 128 * 64) + grp * 4;
  float4 va = *(const float4*)(xb + (iy0 * 128 + ix0) * 64);
  float4 vb = *(const float4*)(xb + (iy1 * 128 + ix0) * 64);
  float4 vc = *(const float4*)(xb + (iy0 * 128 + ix1) * 64);
  float4 vd = *(const float4*)(xb + (iy1 * 128 + ix1) * 64);
  float4 v;
  v.x = wa * va.x + wb * vb.x + wc * vc.x + wd * vd.x;
  v.y = wa * va.y + wb * vb.y + wc * vc.y + wd * vd.y;
  v.z = wa * va.z + wb * vb.z + wc * vc.z + wd * vd.z;
  v.w = wa * va.w + wb * vb.w + wc * vc.w + wd * vd.w;
  ushort4v r;
  r.x = f2bf(v.x);
  r.y = f2bf(v.y);
  r.z = f2bf(v.z);
  r.w = f2bf(v.w);
  *(ushort4v*)(sampled + (size_t)pr * 576 + tap * 64 + grp * 4) = r;
}

// ---- GEMM: out[M,128] = sampled[M,576](bf16) x wbt[128,576]^T (bf16) + bias.
// 128x128 tile, BK=32, fragment-order LDS (lane-contiguous 16B slots).
__global__ __launch_bounds__(256) void gemm128(const unsigned short* __restrict__ A,
                                               const unsigned short* __restrict__ Bt,
                                               const float* __restrict__ bias,
                                               float* __restrict__ out,
                                               int p0) {
  __shared__ unsigned short lA[4096];  // 128 rows x 32 k, fragment order
  __shared__ unsigned short lB[4096];
  const int tid = threadIdx.x;
  const int mloc = blockIdx.x * 128;       // row offset within this chunk
  const int m0 = p0 + mloc;                // global output row
  const int lane = tid & 63, wv = tid >> 6;
  const int wi = wv >> 1, wj = wv & 1;
  f32x4 acc[4][4] = {};
  const int r1 = tid >> 2, q = tid & 3;
  const int r2 = r1 + 64;
  const int slot1 = ((r1 >> 4) * 64 + (q << 4) + (r1 & 15)) * 8;
  const int slot2 = ((r2 >> 4) * 64 + (q << 4) + (r2 & 15)) * 8;

  for (int kt = 0; kt < 576; kt += 32) {
    const uint4* ga1 = (const uint4*)(A + (size_t)(mloc + r1) * 576 + kt + q * 8);
    const uint4* ga2 = (const uint4*)(A + (size_t)(mloc + r2) * 576 + kt + q * 8);
    const uint4* gb1 = (const uint4*)(Bt + (size_t)r1 * 576 + kt + q * 8);
    const uint4* gb2 = (const uint4*)(Bt + (size_t)r2 * 576 + kt + q * 8);
    *(uint4*)&lA[slot1] = *ga1;
    *(uint4*)&lA[slot2] = *ga2;
    *(uint4*)&lB[slot1] = *gb1;
    *(uint4*)&lB[slot2] = *gb2;
    __syncthreads();
    short8 av[4], bv[4];
#pragma unroll
    for (int it = 0; it < 4; ++it)
      av[it] = *(const short8*)&lA[((wi * 4 + it) * 64 + lane) * 8];
#pragma unroll
    for (int jt = 0; jt < 4; ++jt)
      bv[jt] = *(const short8*)&lB[((wj * 4 + jt) * 64 + lane) * 8];
#pragma unroll
    for (int it = 0; it < 4; ++it)
#pragma unroll
      for (int jt = 0; jt < 4; ++jt)
        acc[it][jt] = __builtin_amdgcn_mfma_f32_16x16x32_bf16(av[it], bv[jt],
                                                              acc[it][jt], 0, 0, 0);
    __syncthreads();
  }
#pragma unroll
  for (int it = 0; it < 4; ++it) {
    int m = m0 + wi * 64 + it * 16 + (lane >> 4) * 4;
#pragma unroll
    for (int jt = 0; jt < 4; ++jt) {
      int n = wj * 64 + jt * 16 + (lane & 15);
      float bn = bias[n];
#pragma unroll
      for (int r = 0; r < 4; ++r)
        out[(size_t)(m + r) * 128 + n] = acc[it][jt][r] + bn;
    }
  }
}

extern "C" void kernel_launch(void* const* d_in, const int* in_sizes, int n_in,
                              void* d_out, int out_size, void* d_ws, size_t ws_size,
                              hipStream_t stream) {
  const float* x = (const float*)d_in[0];
  const float* w_off = (const float*)d_in[1];
  const float* b_off = (const float*)d_in[2];
  const float* w_out = (const float*)d_in[3];
  const float* b_out = (const float*)d_in[4];
  float* out = (float*)d_out;

  char* ws = (char*)d_ws;
  float* offs = (float*)ws;                              // 131072*18*4 = 9,437,184
  float* wT = (float*)(ws + 9437184);                    // 10368*4     =    41,472
  unsigned short* wbt = (unsigned short*)(ws + 9478656); // 73728*2     =   147,456
  unsigned short* sampled = (unsigned short*)(ws + 9626112);

  prep<<<329, 256, 0, stream>>>(w_off, w_out, wT, wbt);
  // 512 blocks x 1024 threads; bid&7 = image -> XCD chunking; 2 rows/block.
  offconv6<<<512, 1024, 0, stream>>>(x, wT, b_off, offs);

  // chunk sample->gemm through whatever workspace remains (stream-serialized,
  // ws_size is constant so the launch sequence is identical every call).
  const int TOTAL_PX = 131072;
  size_t avail = (ws_size > 9626112) ? ws_size - 9626112 : 0;
  long cp = (long)(avail / (576 * 2));
  cp &= ~127L;  // multiple of 128
  if (cp < 128) cp = 128;          // minimal chunk; assumes ws >= ~10 MB
  if (cp > TOTAL_PX) cp = TOTAL_PX;
  int chunk_px = (int)cp;
  for (int pbase = 0; pbase < TOTAL_PX; pbase += chunk_px) {
    int npx = TOTAL_PX - pbase;
    if (npx > chunk_px) npx = chunk_px;
    // lane-tasks = npx*9*16 (16 lanes per (px,tap)); 256 threads/block.
    sample2<<<npx * 9 / 16, 256, 0, stream>>>(x, offs, sampled, pbase);
    gemm128<<<npx / 128, 256, 0, stream>>>(sampled, wbt, b_out, out, pbase);
  }
}

// Round 7
// 239.140 us; speedup vs baseline: 1.7125x; 1.7125x over previous
//
#include <hip/hip_runtime.h>

typedef short short8 __attribute__((ext_vector_type(8)));
typedef float f32x4 __attribute__((ext_vector_type(4)));
typedef unsigned short ushort4v __attribute__((ext_vector_type(4)));

__device__ __forceinline__ unsigned short f2bf(float f) {
  unsigned int u = __builtin_bit_cast(unsigned int, f);
  u += 0x7fffu + ((u >> 16) & 1u);   // round-to-nearest-even
  return (unsigned short)(u >> 16);
}

// DPP row_shr add: v += lane(i-N) within the 16-lane row (zero-fill OOB).
// After 0x114,0x112,0x111 lane 7 of each 8-lane group holds that group's sum.
template <int CTRL>
__device__ __forceinline__ float dpp_add(float v) {
  int t = __builtin_amdgcn_update_dpp(0, __builtin_bit_cast(int, v), CTRL, 0xf, 0xf, true);
  return v + __builtin_bit_cast(float, t);
}

// ---- prep: transpose w_off [pos][c][18] -> wT [pos][18][c], convert w_out
// [576][128] fp32 -> wbt [128][576] bf16 (B^T for the GEMM).
__global__ __launch_bounds__(256) void prep(const float* __restrict__ w_off,
                                            const float* __restrict__ w_out,
                                            float* __restrict__ wT,
                                            unsigned short* __restrict__ wbt) {
  int i = blockIdx.x * 256 + threadIdx.x;
  if (i < 73728) {  // 576*128
    int k = i >> 7, n = i & 127;
    wbt[n * 576 + k] = f2bf(w_out[i]);
  }
  int t = i - 73728;
  if (t >= 0 && t < 10368) {  // 9*64*18
    int pos = t / 1152, r = t - pos * 1152;
    int c = r / 18, j = r - c * 18;
    wT[(pos * 18 + j) * 64 + c] = w_off[t];
  }
}

// ---- offset conv v7: v4's proven body (pair/thread, acc[18][2], 56 VGPR
// no-spill) + wT in LDS + 512-thread blocks at a SAFE register budget.
// Register-pressure ledger from 6 attempts: body needs ~56-60 VGPR.
//   v2: full unroll -> load batching -> 256 VGPR + spills.
//   v3: partial unroll -> runtime acc index -> acc in scratch.
//   v4: 107us CLEAN (56 VGPR @ (256,4)=128 cap) but wT re-reads thrash L1.
//   v5: acc[18][4]=72 -> spill. v6: (1024,8) -> 64/32-VGPR budget -> spill.
// v7: (512,4) -> 128-VGPR budget (fits 60 with 2x margin); LDS 41.5KB/block
// -> 3 blocks/CU = 24 waves/CU (75%); w reads become broadcast ds_read_b128.
__global__ __launch_bounds__(512, 4) void offconv7(const float* __restrict__ x,
                                                   const float* __restrict__ wT,
                                                   const float* __restrict__ b_off,
                                                   float* __restrict__ offs) {
  __shared__ float lw[10368];  // [tap][18][64] = 41,472 B
  const int tid = threadIdx.x;
#pragma unroll 1
  for (int i = tid; i < 2592; i += 512)
    *(float4*)&lw[i * 4] = *(const float4*)&wT[i * 4];
  __syncthreads();

  const int row = (blockIdx.x & 7) * 128 + (blockIdx.x >> 3);  // img -> XCD
  const int img = row >> 7, h = row & 127;
  const int pairLocal = tid >> 3;        // 0..63 (pair within row)
  const int c8 = tid & 7;                // channel group
  const int w0 = pairLocal * 2;
  const int p = row * 128 + w0;

  float acc[18][2];
#pragma unroll
  for (int j = 0; j < 18; ++j) {
    float bj = b_off[j];
    acc[j][0] = bj;
    acc[j][1] = bj;
  }

  const float* xim = x + (size_t)img * (128 * 128 * 64);
  const int ca = c8 * 4;  // this lane's channels: ca..ca+3, ca+32..ca+35

#pragma unroll 1
  for (int kh = 0; kh < 3; ++kh) {
    const int hh = h + kh - 1;
    const bool rok = (hh >= 0) && (hh <= 127);
    const int hc = hh < 0 ? 0 : (hh > 127 ? 127 : hh);
#pragma unroll 1
    for (int kw = 0; kw < 3; ++kw) {
      const int ww0 = w0 + kw - 1;  // in [-1,127] (w0 even <= 126)
      const int ww1 = ww0 + 1;      // in [0,128]
      const bool ok0 = rok && (ww0 >= 0);
      const bool ok1 = rok && (ww1 <= 127);
      const int wc0 = ww0 < 0 ? 0 : ww0;
      const int wc1 = ww1 > 127 ? 127 : ww1;
      const float* x0 = xim + (size_t)(hc * 128 + wc0) * 64 + ca;
      const float* x1 = xim + (size_t)(hc * 128 + wc1) * 64 + ca;
      float4 xa0 = *(const float4*)x0;
      float4 xb0 = *(const float4*)(x0 + 32);
      float4 xa1 = *(const float4*)x1;
      float4 xb1 = *(const float4*)(x1 + 32);
      if (!ok0) { xa0 = make_float4(0.f, 0.f, 0.f, 0.f); xb0 = xa0; }
      if (!ok1) { xa1 = make_float4(0.f, 0.f, 0.f, 0.f); xb1 = xa1; }
      const float* wp = lw + ((kh * 3 + kw) * 18) * 64 + ca;
#pragma unroll
      for (int j = 0; j < 18; ++j) {  // FULL unroll: acc index is static
        float4 wa = *(const float4*)(wp + j * 64);
        float4 wb = *(const float4*)(wp + j * 64 + 32);
        float a0 = acc[j][0], a1 = acc[j][1];
        a0 = fmaf(xa0.x, wa.x, a0);
        a0 = fmaf(xa0.y, wa.y, a0);
        a0 = fmaf(xa0.z, wa.z, a0);
        a0 = fmaf(xa0.w, wa.w, a0);
        a0 = fmaf(xb0.x, wb.x, a0);
        a0 = fmaf(xb0.y, wb.y, a0);
        a0 = fmaf(xb0.z, wb.z, a0);
        a0 = fmaf(xb0.w, wb.w, a0);
        a1 = fmaf(xa1.x, wa.x, a1);
        a1 = fmaf(xa1.y, wa.y, a1);
        a1 = fmaf(xa1.z, wa.z, a1);
        a1 = fmaf(xa1.w, wa.w, a1);
        a1 = fmaf(xb1.x, wb.x, a1);
        a1 = fmaf(xb1.y, wb.y, a1);
        a1 = fmaf(xb1.z, wb.z, a1);
        a1 = fmaf(xb1.w, wb.w, a1);
        acc[j][0] = a0;
        acc[j][1] = a1;
      }
    }
  }

  // reduce channel partials across the 8 c8-lanes; total lands in c8==7.
#pragma unroll
  for (int j = 0; j < 18; ++j) {
#pragma unroll
    for (int q = 0; q < 2; ++q) {
      float v = acc[j][q];
      v = dpp_add<0x114>(v);  // row_shr:4
      v = dpp_add<0x112>(v);  // row_shr:2
      v = dpp_add<0x111>(v);  // row_shr:1
      acc[j][q] = v;
    }
  }
  if (c8 == 7) {
    float* op = offs + (size_t)p * 18;
#pragma unroll
    for (int j = 0; j < 18; ++j) {
      op[j] = acc[j][0];
      op[18 + j] = acc[j][1];
    }
  }
}

// ---- bilinear sampling v2: lane = 4 channels (float4), 16-lane group per
// (pixel, tap), wave covers 4 taps. (R3: v1 was VALU-issue-bound at 86%;
// v2 amortizes per-tap scalar math 4x and cuts VMEM instrs 4x.)
__global__ __launch_bounds__(256) void sample2(const float* __restrict__ x,
                                               const float* __restrict__ offs,
                                               unsigned short* __restrict__ sampled,
                                               int p0) {
  int gid = blockIdx.x * 256 + threadIdx.x;
  int grp = gid & 15;        // channel group: channels grp*4 .. grp*4+3
  int tt = gid >> 4;         // tap-task index (relative)
  int pr = tt / 9;           // pixel relative to p0 (magic-mul div)
  int tap = tt - pr * 9;
  int p = p0 + pr;
  int b = p >> 14, hw = p & 16383, h = hw >> 7, w = hw & 127;
  float2 o = *(const float2*)(offs + (size_t)p * 18 + tap * 2);
  float fx = fminf(fmaxf((float)w + o.x, 0.f), 127.f);
  float fy = fminf(fmaxf((float)h + o.y, 0.f), 127.f);
  float x0 = floorf(fx), y0 = floorf(fy);
  float x1 = fminf(x0 + 1.f, 127.f), y1 = fminf(y0 + 1.f, 127.f);
  float wx1 = x1 - fx, wx0 = fx - x0;
  float wy1 = y1 - fy, wy0 = fy - y0;
  float wa = wx1 * wy1, wb = wx1 * wy0, wc = wx0 * wy1, wd = wx0 * wy0;
  int ix0 = (int)x0, ix1 = (int)x1, iy0 = (int)y0, iy1 = (int)y1;
  const float* xb = x + (size_t)b * (128 * 128 * 64) + grp * 4;
  float4 va = *(const float4*)(xb + (iy0 * 128 + ix0) * 64);
  float4 vb = *(const float4*)(xb + (iy1 * 128 + ix0) * 64);
  float4 vc = *(const float4*)(xb + (iy0 * 128 + ix1) * 64);
  float4 vd = *(const float4*)(xb + (iy1 * 128 + ix1) * 64);
  float4 v;
  v.x = wa * va.x + wb * vb.x + wc * vc.x + wd * vd.x;
  v.y = wa * va.y + wb * vb.y + wc * vc.y + wd * vd.y;
  v.z = wa * va.z + wb * vb.z + wc * vc.z + wd * vd.z;
  v.w = wa * va.w + wb * vb.w + wc * vc.w + wd * vd.w;
  ushort4v r;
  r.x = f2bf(v.x);
  r.y = f2bf(v.y);
  r.z = f2bf(v.z);
  r.w = f2bf(v.w);
  *(ushort4v*)(sampled + (size_t)pr * 576 + tap * 64 + grp * 4) = r;
}

// ---- GEMM: out[M,128] = sampled[M,576](bf16) x wbt[128,576]^T (bf16) + bias.
// 128x128 tile, BK=32, fragment-order LDS (lane-contiguous 16B slots).
__global__ __launch_bounds__(256) void gemm128(const unsigned short* __restrict__ A,
                                               const unsigned short* __restrict__ Bt,
                                               const float* __restrict__ bias,
                                               float* __restrict__ out,
                                               int p0) {
  __shared__ unsigned short lA[4096];  // 128 rows x 32 k, fragment order
  __shared__ unsigned short lB[4096];
  const int tid = threadIdx.x;
  const int mloc = blockIdx.x * 128;       // row offset within this chunk
  const int m0 = p0 + mloc;                // global output row
  const int lane = tid & 63, wv = tid >> 6;
  const int wi = wv >> 1, wj = wv & 1;
  f32x4 acc[4][4] = {};
  const int r1 = tid >> 2, q = tid & 3;
  const int r2 = r1 + 64;
  const int slot1 = ((r1 >> 4) * 64 + (q << 4) + (r1 & 15)) * 8;
  const int slot2 = ((r2 >> 4) * 64 + (q << 4) + (r2 & 15)) * 8;

  for (int kt = 0; kt < 576; kt += 32) {
    const uint4* ga1 = (const uint4*)(A + (size_t)(mloc + r1) * 576 + kt + q * 8);
    const uint4* ga2 = (const uint4*)(A + (size_t)(mloc + r2) * 576 + kt + q * 8);
    const uint4* gb1 = (const uint4*)(Bt + (size_t)r1 * 576 + kt + q * 8);
    const uint4* gb2 = (const uint4*)(Bt + (size_t)r2 * 576 + kt + q * 8);
    *(uint4*)&lA[slot1] = *ga1;
    *(uint4*)&lA[slot2] = *ga2;
    *(uint4*)&lB[slot1] = *gb1;
    *(uint4*)&lB[slot2] = *gb2;
    __syncthreads();
    short8 av[4], bv[4];
#pragma unroll
    for (int it = 0; it < 4; ++it)
      av[it] = *(const short8*)&lA[((wi * 4 + it) * 64 + lane) * 8];
#pragma unroll
    for (int jt = 0; jt < 4; ++jt)
      bv[jt] = *(const short8*)&lB[((wj * 4 + jt) * 64 + lane) * 8];
#pragma unroll
    for (int it = 0; it < 4; ++it)
#pragma unroll
      for (int jt = 0; jt < 4; ++jt)
        acc[it][jt] = __builtin_amdgcn_mfma_f32_16x16x32_bf16(av[it], bv[jt],
                                                              acc[it][jt], 0, 0, 0);
    __syncthreads();
  }
#pragma unroll
  for (int it = 0; it < 4; ++it) {
    int m = m0 + wi * 64 + it * 16 + (lane >> 4) * 4;
#pragma unroll
    for (int jt = 0; jt < 4; ++jt) {
      int n = wj * 64 + jt * 16 + (lane & 15);
      float bn = bias[n];
#pragma unroll
      for (int r = 0; r < 4; ++r)
        out[(size_t)(m + r) * 128 + n] = acc[it][jt][r] + bn;
    }
  }
}

extern "C" void kernel_launch(void* const* d_in, const int* in_sizes, int n_in,
                              void* d_out, int out_size, void* d_ws, size_t ws_size,
                              hipStream_t stream) {
  const float* x = (const float*)d_in[0];
  const float* w_off = (const float*)d_in[1];
  const float* b_off = (const float*)d_in[2];
  const float* w_out = (const float*)d_in[3];
  const float* b_out = (const float*)d_in[4];
  float* out = (float*)d_out;

  char* ws = (char*)d_ws;
  float* offs = (float*)ws;                              // 131072*18*4 = 9,437,184
  float* wT = (float*)(ws + 9437184);                    // 10368*4     =    41,472
  unsigned short* wbt = (unsigned short*)(ws + 9478656); // 73728*2     =   147,456
  unsigned short* sampled = (unsigned short*)(ws + 9626112);

  prep<<<329, 256, 0, stream>>>(w_off, w_out, wT, wbt);
  // 1024 blocks x 512 threads; one row/block; bid&7 = image -> XCD chunking.
  offconv7<<<1024, 512, 0, stream>>>(x, wT, b_off, offs);

  // chunk sample->gemm through whatever workspace remains (stream-serialized,
  // ws_size is constant so the launch sequence is identical every call).
  const int TOTAL_PX = 131072;
  size_t avail = (ws_size > 9626112) ? ws_size - 9626112 : 0;
  long cp = (long)(avail / (576 * 2));
  cp &= ~127L;  // multiple of 128
  if (cp < 128) cp = 128;          // minimal chunk; assumes ws >= ~10 MB
  if (cp > TOTAL_PX) cp = TOTAL_PX;
  int chunk_px = (int)cp;
  for (int pbase = 0; pbase < TOTAL_PX; pbase += chunk_px) {
    int npx = TOTAL_PX - pbase;
    if (npx > chunk_px) npx = chunk_px;
    // lane-tasks = npx*9*16 (16 lanes per (px,tap)); 256 threads/block.
    sample2<<<npx * 9 / 16, 256, 0, stream>>>(x, offs, sampled, pbase);
    gemm128<<<npx / 128, 256, 0, stream>>>(sampled, wbt, b_out, out, pbase);
  }
}

// Round 8
// 218.575 us; speedup vs baseline: 1.8736x; 1.0941x over previous
//
#include <hip/hip_runtime.h>

typedef short short8 __attribute__((ext_vector_type(8)));
typedef float f32x4 __attribute__((ext_vector_type(4)));

__device__ __forceinline__ unsigned short f2bf(float f) {
  unsigned int u = __builtin_bit_cast(unsigned int, f);
  u += 0x7fffu + ((u >> 16) & 1u);   // round-to-nearest-even
  return (unsigned short)(u >> 16);
}

// DPP row_shr add: v += lane(i-N) within the 16-lane row (zero-fill OOB).
// After 0x114,0x112,0x111 lane 7 of each 8-lane group holds that group's sum.
template <int CTRL>
__device__ __forceinline__ float dpp_add(float v) {
  int t = __builtin_amdgcn_update_dpp(0, __builtin_bit_cast(int, v), CTRL, 0xf, 0xf, true);
  return v + __builtin_bit_cast(float, t);
}

// ---- prep: transpose w_off [pos][c][18] -> wT [pos][18][c], convert w_out
// [576][128] fp32 -> wbt [128][576] bf16 (B^T for the GEMM).
__global__ __launch_bounds__(256) void prep(const float* __restrict__ w_off,
                                            const float* __restrict__ w_out,
                                            float* __restrict__ wT,
                                            unsigned short* __restrict__ wbt) {
  int i = blockIdx.x * 256 + threadIdx.x;
  if (i < 73728) {  // 576*128
    int k = i >> 7, n = i & 127;
    wbt[n * 576 + k] = f2bf(w_out[i]);
  }
  int t = i - 73728;
  if (t >= 0 && t < 10368) {  // 9*64*18
    int pos = t / 1152, r = t - pos * 1152;
    int c = r / 18, j = r - c * 18;
    wT[(pos * 18 + j) * 64 + c] = w_off[t];
  }
}

// ---- offset conv v7 (UNCHANGED from R7, clean): pair/thread acc[18][2],
// wT in LDS, 512 threads @ (512,4) = 128-VGPR budget, XCD-chunked rows.
__global__ __launch_bounds__(512, 4) void offconv7(const float* __restrict__ x,
                                                   const float* __restrict__ wT,
                                                   const float* __restrict__ b_off,
                                                   float* __restrict__ offs) {
  __shared__ float lw[10368];  // [tap][18][64] = 41,472 B
  const int tid = threadIdx.x;
#pragma unroll 1
  for (int i = tid; i < 2592; i += 512)
    *(float4*)&lw[i * 4] = *(const float4*)&wT[i * 4];
  __syncthreads();

  const int row = (blockIdx.x & 7) * 128 + (blockIdx.x >> 3);  // img -> XCD
  const int img = row >> 7, h = row & 127;
  const int pairLocal = tid >> 3;        // 0..63 (pair within row)
  const int c8 = tid & 7;                // channel group
  const int w0 = pairLocal * 2;
  const int p = row * 128 + w0;

  float acc[18][2];
#pragma unroll
  for (int j = 0; j < 18; ++j) {
    float bj = b_off[j];
    acc[j][0] = bj;
    acc[j][1] = bj;
  }

  const float* xim = x + (size_t)img * (128 * 128 * 64);
  const int ca = c8 * 4;  // this lane's channels: ca..ca+3, ca+32..ca+35

#pragma unroll 1
  for (int kh = 0; kh < 3; ++kh) {
    const int hh = h + kh - 1;
    const bool rok = (hh >= 0) && (hh <= 127);
    const int hc = hh < 0 ? 0 : (hh > 127 ? 127 : hh);
#pragma unroll 1
    for (int kw = 0; kw < 3; ++kw) {
      const int ww0 = w0 + kw - 1;  // in [-1,127] (w0 even <= 126)
      const int ww1 = ww0 + 1;      // in [0,128]
      const bool ok0 = rok && (ww0 >= 0);
      const bool ok1 = rok && (ww1 <= 127);
      const int wc0 = ww0 < 0 ? 0 : ww0;
      const int wc1 = ww1 > 127 ? 127 : ww1;
      const float* x0 = xim + (size_t)(hc * 128 + wc0) * 64 + ca;
      const float* x1 = xim + (size_t)(hc * 128 + wc1) * 64 + ca;
      float4 xa0 = *(const float4*)x0;
      float4 xb0 = *(const float4*)(x0 + 32);
      float4 xa1 = *(const float4*)x1;
      float4 xb1 = *(const float4*)(x1 + 32);
      if (!ok0) { xa0 = make_float4(0.f, 0.f, 0.f, 0.f); xb0 = xa0; }
      if (!ok1) { xa1 = make_float4(0.f, 0.f, 0.f, 0.f); xb1 = xa1; }
      const float* wp = lw + ((kh * 3 + kw) * 18) * 64 + ca;
#pragma unroll
      for (int j = 0; j < 18; ++j) {  // FULL unroll: acc index is static
        float4 wa = *(const float4*)(wp + j * 64);
        float4 wb = *(const float4*)(wp + j * 64 + 32);
        float a0 = acc[j][0], a1 = acc[j][1];
        a0 = fmaf(xa0.x, wa.x, a0);
        a0 = fmaf(xa0.y, wa.y, a0);
        a0 = fmaf(xa0.z, wa.z, a0);
        a0 = fmaf(xa0.w, wa.w, a0);
        a0 = fmaf(xb0.x, wb.x, a0);
        a0 = fmaf(xb0.y, wb.y, a0);
        a0 = fmaf(xb0.z, wb.z, a0);
        a0 = fmaf(xb0.w, wb.w, a0);
        a1 = fmaf(xa1.x, wa.x, a1);
        a1 = fmaf(xa1.y, wa.y, a1);
        a1 = fmaf(xa1.z, wa.z, a1);
        a1 = fmaf(xa1.w, wa.w, a1);
        a1 = fmaf(xb1.x, wb.x, a1);
        a1 = fmaf(xb1.y, wb.y, a1);
        a1 = fmaf(xb1.z, wb.z, a1);
        a1 = fmaf(xb1.w, wb.w, a1);
        acc[j][0] = a0;
        acc[j][1] = a1;
      }
    }
  }

  // reduce channel partials across the 8 c8-lanes; total lands in c8==7.
#pragma unroll
  for (int j = 0; j < 18; ++j) {
#pragma unroll
    for (int q = 0; q < 2; ++q) {
      float v = acc[j][q];
      v = dpp_add<0x114>(v);  // row_shr:4
      v = dpp_add<0x112>(v);  // row_shr:2
      v = dpp_add<0x111>(v);  // row_shr:1
      acc[j][q] = v;
    }
  }
  if (c8 == 7) {
    float* op = offs + (size_t)p * 18;
#pragma unroll
    for (int j = 0; j < 18; ++j) {
      op[j] = acc[j][0];
      op[18 + j] = acc[j][1];
    }
  }
}

// ---- FUSED sample+GEMM: one block per 128-px row tile. Per tap (BK=64):
// sample 128 px x 64 ch bilinear directly into fragment-order LDS (exact
// sample2 arithmetic: 16-lane group per px, lane = 4 channels), stage the
// matching 128x64 chunk of wbt, then the verified MFMA path (2 k-halves).
// Kills the 151MB sampled buffer and its write+read HBM round-trip (~48us)
// and overlaps sampling VALU with MFMA. Register ledger: tap loop unroll 1,
// px loop unroll 2, acc statically indexed; no occupancy forcing.
__global__ __launch_bounds__(256) void fused_sg(const float* __restrict__ x,
                                                const float* __restrict__ offs,
                                                const unsigned short* __restrict__ Bt,
                                                const float* __restrict__ bias,
                                                float* __restrict__ out) {
  __shared__ unsigned short lA[2][4096];  // per k-half: 128 rows x 32 k, frag order
  __shared__ unsigned short lB[2][4096];
  const int tid = threadIdx.x;
  const int img = blockIdx.x & 7;        // image -> XCD chunk
  const int rowi = blockIdx.x >> 3;      // row within image
  const int mloc = (img * 128 + rowi) * 128;  // global pixel/base row
  const int lane = tid & 63, wv = tid >> 6;
  const int wi = wv >> 1, wj = wv & 1;
  f32x4 acc[4][4] = {};
  // B staging slots (identical math to the verified gemm128)
  const int r1 = tid >> 2, q = tid & 3;
  const int r2 = r1 + 64;
  const int slot1 = ((r1 >> 4) * 64 + (q << 4) + (r1 & 15)) * 8;
  const int slot2 = ((r2 >> 4) * 64 + (q << 4) + (r2 & 15)) * 8;
  // sampling lane mapping: group g handles px g*8..g*8+7; lane c4 = 4 channels
  const int g = tid >> 4;
  const int c4 = tid & 15;
  const int ahalf = c4 >> 3;          // which 32-k half this lane's channels hit
  const int aq = (c4 >> 1) & 3;       // 8-k sub-slot
  const int asub = (c4 & 1) * 4;      // ushort offset within the 16B slot
  const float* xim = x + (size_t)img * (128 * 128 * 64) + c4 * 4;
  const float hf = (float)rowi;

#pragma unroll 1
  for (int tap = 0; tap < 9; ++tap) {
    const int kt = tap * 64;
    // issue B loads early; ds_write them after the sampling phase
    uint4 b00 = *(const uint4*)(Bt + (size_t)r1 * 576 + kt + q * 8);
    uint4 b01 = *(const uint4*)(Bt + (size_t)r2 * 576 + kt + q * 8);
    uint4 b10 = *(const uint4*)(Bt + (size_t)r1 * 576 + kt + 32 + q * 8);
    uint4 b11 = *(const uint4*)(Bt + (size_t)r2 * 576 + kt + 32 + q * 8);
    // sample this block's 128 px for this tap (8 px per 16-lane group)
#pragma unroll 2
    for (int i = 0; i < 8; ++i) {
      const int w = g * 8 + i;
      const int p = mloc + w;
      float2 o = *(const float2*)(offs + (size_t)p * 18 + tap * 2);
      float fx = fminf(fmaxf((float)w + o.x, 0.f), 127.f);
      float fy = fminf(fmaxf(hf + o.y, 0.f), 127.f);
      float x0f = floorf(fx), y0f = floorf(fy);
      float x1f = fminf(x0f + 1.f, 127.f), y1f = fminf(y0f + 1.f, 127.f);
      float wx1 = x1f - fx, wx0 = fx - x0f;
      float wy1 = y1f - fy, wy0 = fy - y0f;
      float wa = wx1 * wy1, wb = wx1 * wy0, wc = wx0 * wy1, wd = wx0 * wy0;
      int ix0 = (int)x0f, ix1 = (int)x1f, iy0 = (int)y0f, iy1 = (int)y1f;
      float4 va = *(const float4*)(xim + (iy0 * 128 + ix0) * 64);
      float4 vb = *(const float4*)(xim + (iy1 * 128 + ix0) * 64);
      float4 vc = *(const float4*)(xim + (iy0 * 128 + ix1) * 64);
      float4 vd = *(const float4*)(xim + (iy1 * 128 + ix1) * 64);
      float4 v;
      v.x = wa * va.x + wb * vb.x + wc * vc.x + wd * vd.x;
      v.y = wa * va.y + wb * vb.y + wc * vc.y + wd * vd.y;
      v.z = wa * va.z + wb * vb.z + wc * vc.z + wd * vd.z;
      v.w = wa * va.w + wb * vb.w + wc * vc.w + wd * vd.w;
      uint2 pv;
      pv.x = (unsigned)f2bf(v.x) | ((unsigned)f2bf(v.y) << 16);
      pv.y = (unsigned)f2bf(v.z) | ((unsigned)f2bf(v.w) << 16);
      const int slot = ((w >> 4) * 64 + (aq << 4) + (w & 15)) * 8 + asub;
      *(uint2*)&lA[ahalf][slot] = pv;  // 8B, 8B-aligned
    }
    *(uint4*)&lB[0][slot1] = b00;
    *(uint4*)&lB[0][slot2] = b01;
    *(uint4*)&lB[1][slot1] = b10;
    *(uint4*)&lB[1][slot2] = b11;
    __syncthreads();
#pragma unroll
    for (int hh = 0; hh < 2; ++hh) {
      short8 av[4], bv[4];
#pragma unroll
      for (int it = 0; it < 4; ++it)
        av[it] = *(const short8*)&lA[hh][((wi * 4 + it) * 64 + lane) * 8];
#pragma unroll
      for (int jt = 0; jt < 4; ++jt)
        bv[jt] = *(const short8*)&lB[hh][((wj * 4 + jt) * 64 + lane) * 8];
#pragma unroll
      for (int it = 0; it < 4; ++it)
#pragma unroll
        for (int jt = 0; jt < 4; ++jt)
          acc[it][jt] = __builtin_amdgcn_mfma_f32_16x16x32_bf16(av[it], bv[jt],
                                                                acc[it][jt], 0, 0, 0);
    }
    __syncthreads();
  }
#pragma unroll
  for (int it = 0; it < 4; ++it) {
    int m = mloc + wi * 64 + it * 16 + (lane >> 4) * 4;
#pragma unroll
    for (int jt = 0; jt < 4; ++jt) {
      int n = wj * 64 + jt * 16 + (lane & 15);
      float bn = bias[n];
#pragma unroll
      for (int r = 0; r < 4; ++r)
        out[(size_t)(m + r) * 128 + n] = acc[it][jt][r] + bn;
    }
  }
}

extern "C" void kernel_launch(void* const* d_in, const int* in_sizes, int n_in,
                              void* d_out, int out_size, void* d_ws, size_t ws_size,
                              hipStream_t stream) {
  const float* x = (const float*)d_in[0];
  const float* w_off = (const float*)d_in[1];
  const float* b_off = (const float*)d_in[2];
  const float* w_out = (const float*)d_in[3];
  const float* b_out = (const float*)d_in[4];
  float* out = (float*)d_out;

  char* ws = (char*)d_ws;
  float* offs = (float*)ws;                              // 131072*18*4 = 9,437,184
  float* wT = (float*)(ws + 9437184);                    // 10368*4     =    41,472
  unsigned short* wbt = (unsigned short*)(ws + 9478656); // 73728*2     =   147,456

  prep<<<329, 256, 0, stream>>>(w_off, w_out, wT, wbt);
  // 1024 blocks x 512 threads; one row/block; bid&7 = image -> XCD chunking.
  offconv7<<<1024, 512, 0, stream>>>(x, wT, b_off, offs);
  // fused sample+GEMM: 1024 blocks (one 128-px row tile each), same XCD map.
  fused_sg<<<1024, 256, 0, stream>>>(x, offs, wbt, b_out, out);
}

// Round 10
// 216.477 us; speedup vs baseline: 1.8918x; 1.0097x over previous
//
#include <hip/hip_runtime.h>

typedef short short8 __attribute__((ext_vector_type(8)));
typedef float f32x4 __attribute__((ext_vector_type(4)));

__device__ __forceinline__ unsigned short f2bf(float f) {
  unsigned int u = __builtin_bit_cast(unsigned int, f);
  u += 0x7fffu + ((u >> 16) & 1u);   // round-to-nearest-even
  return (unsigned short)(u >> 16);
}

// DPP row_shr add: v += lane(i-N) within the 16-lane row (zero-fill OOB).
// After 0x114,0x112,0x111 lane 7 of each 8-lane group holds that group's sum.
template <int CTRL>
__device__ __forceinline__ float dpp_add(float v) {
  int t = __builtin_amdgcn_update_dpp(0, __builtin_bit_cast(int, v), CTRL, 0xf, 0xf, true);
  return v + __builtin_bit_cast(float, t);
}

// ---- prep: transpose w_off [pos][c][18] -> wT [pos][18][c], convert w_out
// [576][128] fp32 -> wbt [128][576] bf16 (B^T for the GEMM).
__global__ __launch_bounds__(256) void prep(const float* __restrict__ w_off,
                                            const float* __restrict__ w_out,
                                            float* __restrict__ wT,
                                            unsigned short* __restrict__ wbt) {
  int i = blockIdx.x * 256 + threadIdx.x;
  if (i < 73728) {  // 576*128
    int k = i >> 7, n = i & 127;
    wbt[n * 576 + k] = f2bf(w_out[i]);
  }
  int t = i - 73728;
  if (t >= 0 && t < 10368) {  // 9*64*18
    int pos = t / 1152, r = t - pos * 1152;
    int c = r / 18, j = r - c * 18;
    wT[(pos * 18 + j) * 64 + c] = w_off[t];
  }
}

// ---- offset conv v7 (UNCHANGED from R7, clean): pair/thread acc[18][2],
// wT in LDS, 512 threads @ (512,4) = 128-VGPR budget, XCD-chunked rows.
__global__ __launch_bounds__(512, 4) void offconv7(const float* __restrict__ x,
                                                   const float* __restrict__ wT,
                                                   const float* __restrict__ b_off,
                                                   float* __restrict__ offs) {
  __shared__ float lw[10368];  // [tap][18][64] = 41,472 B
  const int tid = threadIdx.x;
#pragma unroll 1
  for (int i = tid; i < 2592; i += 512)
    *(float4*)&lw[i * 4] = *(const float4*)&wT[i * 4];
  __syncthreads();

  const int row = (blockIdx.x & 7) * 128 + (blockIdx.x >> 3);  // img -> XCD
  const int img = row >> 7, h = row & 127;
  const int pairLocal = tid >> 3;        // 0..63 (pair within row)
  const int c8 = tid & 7;                // channel group
  const int w0 = pairLocal * 2;
  const int p = row * 128 + w0;

  float acc[18][2];
#pragma unroll
  for (int j = 0; j < 18; ++j) {
    float bj = b_off[j];
    acc[j][0] = bj;
    acc[j][1] = bj;
  }

  const float* xim = x + (size_t)img * (128 * 128 * 64);
  const int ca = c8 * 4;  // this lane's channels: ca..ca+3, ca+32..ca+35

#pragma unroll 1
  for (int kh = 0; kh < 3; ++kh) {
    const int hh = h + kh - 1;
    const bool rok = (hh >= 0) && (hh <= 127);
    const int hc = hh < 0 ? 0 : (hh > 127 ? 127 : hh);
#pragma unroll 1
    for (int kw = 0; kw < 3; ++kw) {
      const int ww0 = w0 + kw - 1;  // in [-1,127] (w0 even <= 126)
      const int ww1 = ww0 + 1;      // in [0,128]
      const bool ok0 = rok && (ww0 >= 0);
      const bool ok1 = rok && (ww1 <= 127);
      const int wc0 = ww0 < 0 ? 0 : ww0;
      const int wc1 = ww1 > 127 ? 127 : ww1;
      const float* x0 = xim + (size_t)(hc * 128 + wc0) * 64 + ca;
      const float* x1 = xim + (size_t)(hc * 128 + wc1) * 64 + ca;
      float4 xa0 = *(const float4*)x0;
      float4 xb0 = *(const float4*)(x0 + 32);
      float4 xa1 = *(const float4*)x1;
      float4 xb1 = *(const float4*)(x1 + 32);
      if (!ok0) { xa0 = make_float4(0.f, 0.f, 0.f, 0.f); xb0 = xa0; }
      if (!ok1) { xa1 = make_float4(0.f, 0.f, 0.f, 0.f); xb1 = xa1; }
      const float* wp = lw + ((kh * 3 + kw) * 18) * 64 + ca;
#pragma unroll
      for (int j = 0; j < 18; ++j) {  // FULL unroll: acc index is static
        float4 wa = *(const float4*)(wp + j * 64);
        float4 wb = *(const float4*)(wp + j * 64 + 32);
        float a0 = acc[j][0], a1 = acc[j][1];
        a0 = fmaf(xa0.x, wa.x, a0);
        a0 = fmaf(xa0.y, wa.y, a0);
        a0 = fmaf(xa0.z, wa.z, a0);
        a0 = fmaf(xa0.w, wa.w, a0);
        a0 = fmaf(xb0.x, wb.x, a0);
        a0 = fmaf(xb0.y, wb.y, a0);
        a0 = fmaf(xb0.z, wb.z, a0);
        a0 = fmaf(xb0.w, wb.w, a0);
        a1 = fmaf(xa1.x, wa.x, a1);
        a1 = fmaf(xa1.y, wa.y, a1);
        a1 = fmaf(xa1.z, wa.z, a1);
        a1 = fmaf(xa1.w, wa.w, a1);
        a1 = fmaf(xb1.x, wb.x, a1);
        a1 = fmaf(xb1.y, wb.y, a1);
        a1 = fmaf(xb1.z, wb.z, a1);
        a1 = fmaf(xb1.w, wb.w, a1);
        acc[j][0] = a0;
        acc[j][1] = a1;
      }
    }
  }

  // reduce channel partials across the 8 c8-lanes; total lands in c8==7.
#pragma unroll
  for (int j = 0; j < 18; ++j) {
#pragma unroll
    for (int q = 0; q < 2; ++q) {
      float v = acc[j][q];
      v = dpp_add<0x114>(v);  // row_shr:4
      v = dpp_add<0x112>(v);  // row_shr:2
      v = dpp_add<0x111>(v);  // row_shr:1
      acc[j][q] = v;
    }
  }
  if (c8 == 7) {
    float* op = offs + (size_t)p * 18;
#pragma unroll
    for (int j = 0; j < 18; ++j) {
      op[j] = acc[j][0];
      op[18 + j] = acc[j][1];
    }
  }
}

// ---- FUSED sample+GEMM v3: exact R8 structure/slot formula (which PASSED),
// with ONE provable delta: pixel-to-lane map w = i*16+g (was g*8+i).
// Proof of equivalence: both enumerate the same (w, c4) write-set per tap and
// slot/content depend only on (w, c4) -> LDS content at the barrier is
// bit-identical to R8; reads untouched. Bank effect: write bank =
// (w&7)*4 + (asub/4)*2; R8 had w&7 = i (same for ALL 64 lanes -> ~32/bank,
// 2.12e7 conflict cycles); now w&7 = g&7 (4 distinct per wave -> 8 banks,
// 8 lanes/bank, ~3x cheaper per m136). R9's XOR swizzle attempt FAILED
// correctness (absmax 0.63) -- algebra looked consistent but empirics win;
// reverted until it can be verified by construction.
__global__ __launch_bounds__(256) void fused_sg(const float* __restrict__ x,
                                                const float* __restrict__ offs,
                                                const unsigned short* __restrict__ Bt,
                                                const float* __restrict__ bias,
                                                float* __restrict__ out) {
  __shared__ unsigned short lA[2][4096];  // per k-half: 128 rows x 32 k, frag order
  __shared__ unsigned short lB[2][4096];
  const int tid = threadIdx.x;
  const int img = blockIdx.x & 7;        // image -> XCD chunk
  const int rowi = blockIdx.x >> 3;      // row within image
  const int mloc = (img * 128 + rowi) * 128;  // global pixel/base row
  const int lane = tid & 63, wv = tid >> 6;
  const int wi = wv >> 1, wj = wv & 1;
  f32x4 acc[4][4] = {};
  // B staging slots (identical math to the verified gemm128; conflict-free)
  const int r1 = tid >> 2, q = tid & 3;
  const int r2 = r1 + 64;
  const int slot1 = ((r1 >> 4) * 64 + (q << 4) + (r1 & 15)) * 8;
  const int slot2 = ((r2 >> 4) * 64 + (q << 4) + (r2 & 15)) * 8;
  // sampling lane mapping: group g = tid>>4 (16 lanes per pixel), lane c4 = 4 ch
  const int g = tid >> 4;
  const int c4 = tid & 15;
  const int ahalf = c4 >> 3;          // which 32-k half this lane's channels hit
  const int aq = (c4 >> 1) & 3;       // 8-k sub-slot
  const int asub = (c4 & 1) * 4;      // ushort offset within the 16B slot
  const float* xim = x + (size_t)img * (128 * 128 * 64) + c4 * 4;
  const float hf = (float)rowi;

#pragma unroll 1
  for (int tap = 0; tap < 9; ++tap) {
    const int kt = tap * 64;
    // issue B loads early; ds_write them after the sampling phase
    uint4 b00 = *(const uint4*)(Bt + (size_t)r1 * 576 + kt + q * 8);
    uint4 b01 = *(const uint4*)(Bt + (size_t)r2 * 576 + kt + q * 8);
    uint4 b10 = *(const uint4*)(Bt + (size_t)r1 * 576 + kt + 32 + q * 8);
    uint4 b11 = *(const uint4*)(Bt + (size_t)r2 * 576 + kt + 32 + q * 8);
    // sample this block's 128 px for this tap (px = i*16 + g)
#pragma unroll 2
    for (int i = 0; i < 8; ++i) {
      const int w = i * 16 + g;
      const int p = mloc + w;
      float2 o = *(const float2*)(offs + (size_t)p * 18 + tap * 2);
      float fx = fminf(fmaxf((float)w + o.x, 0.f), 127.f);
      float fy = fminf(fmaxf(hf + o.y, 0.f), 127.f);
      float x0f = floorf(fx), y0f = floorf(fy);
      float x1f = fminf(x0f + 1.f, 127.f), y1f = fminf(y0f + 1.f, 127.f);
      float wx1 = x1f - fx, wx0 = fx - x0f;
      float wy1 = y1f - fy, wy0 = fy - y0f;
      float wa = wx1 * wy1, wb = wx1 * wy0, wc = wx0 * wy1, wd = wx0 * wy0;
      int ix0 = (int)x0f, ix1 = (int)x1f, iy0 = (int)y0f, iy1 = (int)y1f;
      float4 va = *(const float4*)(xim + (iy0 * 128 + ix0) * 64);
      float4 vb = *(const float4*)(xim + (iy1 * 128 + ix0) * 64);
      float4 vc = *(const float4*)(xim + (iy0 * 128 + ix1) * 64);
      float4 vd = *(const float4*)(xim + (iy1 * 128 + ix1) * 64);
      float4 v;
      v.x = wa * va.x + wb * vb.x + wc * vc.x + wd * vd.x;
      v.y = wa * va.y + wb * vb.y + wc * vc.y + wd * vd.y;
      v.z = wa * va.z + wb * vb.z + wc * vc.z + wd * vd.z;
      v.w = wa * va.w + wb * vb.w + wc * vc.w + wd * vd.w;
      uint2 pv;
      pv.x = (unsigned)f2bf(v.x) | ((unsigned)f2bf(v.y) << 16);
      pv.y = (unsigned)f2bf(v.z) | ((unsigned)f2bf(v.w) << 16);
      // R8's exact slot formula, written as a function of w only:
      const int slot = ((w >> 4) * 64 + (aq << 4) + (w & 15)) * 8 + asub;
      *(uint2*)&lA[ahalf][slot] = pv;  // 8B, 8B-aligned
    }
    *(uint4*)&lB[0][slot1] = b00;
    *(uint4*)&lB[0][slot2] = b01;
    *(uint4*)&lB[1][slot1] = b10;
    *(uint4*)&lB[1][slot2] = b11;
    __syncthreads();
#pragma unroll
    for (int hh = 0; hh < 2; ++hh) {
      short8 av[4], bv[4];
#pragma unroll
      for (int it = 0; it < 4; ++it)
        av[it] = *(const short8*)&lA[hh][((wi * 4 + it) * 64 + lane) * 8];
#pragma unroll
      for (int jt = 0; jt < 4; ++jt)
        bv[jt] = *(const short8*)&lB[hh][((wj * 4 + jt) * 64 + lane) * 8];
#pragma unroll
      for (int it = 0; it < 4; ++it)
#pragma unroll
        for (int jt = 0; jt < 4; ++jt)
          acc[it][jt] = __builtin_amdgcn_mfma_f32_16x16x32_bf16(av[it], bv[jt],
                                                                acc[it][jt], 0, 0, 0);
    }
    __syncthreads();
  }
#pragma unroll
  for (int it = 0; it < 4; ++it) {
    int m = mloc + wi * 64 + it * 16 + (lane >> 4) * 4;
#pragma unroll
    for (int jt = 0; jt < 4; ++jt) {
      int n = wj * 64 + jt * 16 + (lane & 15);
      float bn = bias[n];
#pragma unroll
      for (int r = 0; r < 4; ++r)
        out[(size_t)(m + r) * 128 + n] = acc[it][jt][r] + bn;
    }
  }
}

extern "C" void kernel_launch(void* const* d_in, const int* in_sizes, int n_in,
                              void* d_out, int out_size, void* d_ws, size_t ws_size,
                              hipStream_t stream) {
  const float* x = (const float*)d_in[0];
  const float* w_off = (const float*)d_in[1];
  const float* b_off = (const float*)d_in[2];
  const float* w_out = (const float*)d_in[3];
  const float* b_out = (const float*)d_in[4];
  float* out = (float*)d_out;

  char* ws = (char*)d_ws;
  float* offs = (float*)ws;                              // 131072*18*4 = 9,437,184
  float* wT = (float*)(ws + 9437184);                    // 10368*4     =    41,472
  unsigned short* wbt = (unsigned short*)(ws + 9478656); // 73728*2     =   147,456

  prep<<<329, 256, 0, stream>>>(w_off, w_out, wT, wbt);
  // 1024 blocks x 512 threads; one row/block; bid&7 = image -> XCD chunking.
  offconv7<<<1024, 512, 0, stream>>>(x, wT, b_off, offs);
  // fused sample+GEMM: 1024 blocks (one 128-px row tile each), same XCD map.
  fused_sg<<<1024, 256, 0, stream>>>(x, offs, wbt, b_out, out);
}